// Round 1
// baseline (225.219 us; speedup 1.0000x reference)
//
#include <hip/hip_runtime.h>
#include <hip/hip_bf16.h>

// Problem constants (from reference)
constexpr int NL = 4;        // layers
constexpr int NH = 8;        // heads
constexpr int DP = 63;       // param dim
constexpr int D  = 64;       // full dim
constexpr int B  = 16;       // batch
constexpr int S  = 2048;     // seq
constexpr int CHUNKS = 16;   // row-chunks for partial Gram
constexpr int ROWS_PER_CHUNK = S / CHUNKS; // 128

// ---------------------------------------------------------------------------
// kA: partial Gram matrices.  Gp[c][b][q][r] = sum_{m in chunk c, m != S-1}
//     Z[b,m,q] * Z[b,m,r]
// grid (B, CHUNKS), block 256
// ---------------------------------------------------------------------------
__global__ __launch_bounds__(256) void kA(const float* __restrict__ Z,
                                          float* __restrict__ Gp) {
    const int b = blockIdx.x;
    const int c = blockIdx.y;
    __shared__ float lz[64][64];
    const int t   = threadIdx.x;
    const int col = t & 63;      // r
    const int rb  = t >> 6;      // q base (0..3)

    float acc[16];
#pragma unroll
    for (int k = 0; k < 16; ++k) acc[k] = 0.f;

    const int rowbase = c * ROWS_PER_CHUNK;
    for (int sub = 0; sub < ROWS_PER_CHUNK / 64; ++sub) {
        // stage 64 rows of Z into LDS (coalesced); zero the global last row
#pragma unroll
        for (int k = 0; k < 16; ++k) {
            int row  = rb + 4 * k;
            int grow = rowbase + sub * 64 + row;
            float v  = Z[((size_t)b * S + grow) * D + col];
            if (grow == S - 1) v = 0.f;
            lz[row][col] = v;
        }
        __syncthreads();
        for (int m = 0; m < 64; ++m) {
            float zr = lz[m][col];           // lane-consecutive
#pragma unroll
            for (int k = 0; k < 16; ++k)
                acc[k] += lz[m][rb + 4 * k] * zr;   // broadcast
        }
        __syncthreads();
    }
    float* outp = Gp + ((size_t)(c * B + b)) * (D * D);
#pragma unroll
    for (int k = 0; k < 16; ++k)
        outp[(rb + 4 * k) * D + col] = acc[k];
}

// ---------------------------------------------------------------------------
// kB: per (batch, head): reduce G, build augmented params, compute
//     H[b][j] = Q_full @ G @ P_full^T / (S-1)
// grid (B, NH), block 256.  LDS: 4 x 64x64 f32 = 64 KB.
// ---------------------------------------------------------------------------
__global__ __launch_bounds__(256) void kB(const float* __restrict__ Gp,
                                          const float* __restrict__ allparam,
                                          float* __restrict__ H, int layer) {
    const int b = blockIdx.x;
    const int j = blockIdx.y;
    __shared__ float G[64 * 64];    // G[q][r]
    __shared__ float PfT[64 * 64];  // PfT[r][i] = P_full[i][r]
    __shared__ float Qf[64 * 64];   // Q_full[p][q]
    __shared__ float T[64 * 64];    // T[q][i] = (G @ P_full^T)[q][i]

    const int t   = threadIdx.x;
    const int col = t & 63;
    const int rb  = t >> 6;

    // reduce partial Grams (coalesced)
#pragma unroll
    for (int k = 0; k < 16; ++k) {
        int e = t + 256 * k;
        float s = 0.f;
        for (int c2 = 0; c2 < CHUNKS; ++c2)
            s += Gp[((size_t)(c2 * B + b)) * (D * D) + e];
        G[e] = s;
    }

    // build augmented matrices
    const float* P = allparam + ((size_t)((layer * NH + j) * 2 + 0)) * (DP * DP);
    const float* Q = allparam + ((size_t)((layer * NH + j) * 2 + 1)) * (DP * DP);
#pragma unroll
    for (int k = 0; k < 16; ++k) {
        int e = t + 256 * k;
        int r = e >> 6, i = e & 63;
        // P_full: P in [0:63,0:63], corner [63][63]=1
        float pv = 0.f;
        if (r < DP && i < DP) pv = P[i * DP + r];      // transposed load
        if (r == DP && i == DP) pv = 1.f;
        PfT[e] = pv;
        // Q_full: Q in [0:63,0:63], rest zeros.  e = p*64+q here.
        int p = r, q = i;
        Qf[e] = (p < DP && q < DP) ? Q[p * DP + q] : 0.f;
    }
    __syncthreads();

    // T[q][i] = sum_r G[q][r] * PfT[r][i]
    {
        float acc[16];
#pragma unroll
        for (int k = 0; k < 16; ++k) acc[k] = 0.f;
        for (int r = 0; r < 64; ++r) {
            float pv = PfT[r * 64 + col];     // lane-consecutive
#pragma unroll
            for (int k = 0; k < 16; ++k)
                acc[k] += G[(rb + 4 * k) * 64 + r] * pv;   // broadcast
        }
#pragma unroll
        for (int k = 0; k < 16; ++k)
            T[(rb + 4 * k) * 64 + col] = acc[k];
    }
    __syncthreads();

    // H[p][i] = (1/(S-1)) * sum_q Qf[p][q] * T[q][i]
    {
        const float inv = 1.0f / (float)(S - 1);
        float acc[16];
#pragma unroll
        for (int k = 0; k < 16; ++k) acc[k] = 0.f;
        for (int q = 0; q < 64; ++q) {
            float tv = T[q * 64 + col];       // lane-consecutive
#pragma unroll
            for (int k = 0; k < 16; ++k)
                acc[k] += Qf[(rb + 4 * k) * 64 + q] * tv;  // broadcast
        }
        float* Hout = H + ((size_t)(b * NH + j)) * (D * D);
#pragma unroll
        for (int k = 0; k < 16; ++k)
            Hout[(rb + 4 * k) * 64 + col] = acc[k] * inv;
    }
}

// ---------------------------------------------------------------------------
// kB2: W[b] = I + sum_j H[b][j].   grid (B), block 256
// ---------------------------------------------------------------------------
__global__ __launch_bounds__(256) void kB2(const float* __restrict__ H,
                                           float* __restrict__ W) {
    const int b = blockIdx.x;
    const int t = threadIdx.x;
#pragma unroll
    for (int k = 0; k < 16; ++k) {
        int e = t + 256 * k;
        float s = ((e >> 6) == (e & 63)) ? 1.f : 0.f;
        for (int j = 0; j < NH; ++j)
            s += H[((size_t)(b * NH + j)) * (D * D) + e];
        W[(size_t)b * (D * D) + e] = s;
    }
}

// ---------------------------------------------------------------------------
// kC: Z_new[b] = Z[b] @ W[b]   (safe in-place: each block owns its rows)
// grid (B, S/64), block 256
// ---------------------------------------------------------------------------
__global__ __launch_bounds__(256) void kC(const float* Zin,
                                          const float* __restrict__ W,
                                          float* Zout) {
    const int b    = blockIdx.x;
    const int tile = blockIdx.y;
    __shared__ float lz[64][64];
    __shared__ float lw[64][64];
    const int t   = threadIdx.x;
    const int col = t & 63;
    const int rb  = t >> 6;

#pragma unroll
    for (int k = 0; k < 16; ++k) {
        int e = t + 256 * k;
        lw[e >> 6][e & 63] = W[(size_t)b * (D * D) + e];
    }
    const size_t zbase = ((size_t)b * S + (size_t)tile * 64) * D;
#pragma unroll
    for (int k = 0; k < 16; ++k) {
        int row = rb + 4 * k;
        lz[row][col] = Zin[zbase + (size_t)row * D + col];
    }
    __syncthreads();

    float acc[16];
#pragma unroll
    for (int k = 0; k < 16; ++k) acc[k] = 0.f;
    for (int p = 0; p < 64; ++p) {
        float wv = lw[p][col];                // lane-consecutive
#pragma unroll
        for (int k = 0; k < 16; ++k)
            acc[k] += lz[rb + 4 * k][p] * wv; // broadcast
    }
#pragma unroll
    for (int k = 0; k < 16; ++k) {
        int row = rb + 4 * k;
        Zout[zbase + (size_t)row * D + col] = acc[k];
    }
}

// ---------------------------------------------------------------------------
extern "C" void kernel_launch(void* const* d_in, const int* in_sizes, int n_in,
                              void* d_out, int out_size, void* d_ws, size_t ws_size,
                              hipStream_t stream) {
    const float* Z        = (const float*)d_in[0];
    const float* allparam = (const float*)d_in[1];
    float* out = (float*)d_out;

    // workspace layout (floats)
    float* Gp = (float*)d_ws;                        // CHUNKS*B*4096 = 4 MB
    float* H  = Gp + (size_t)CHUNKS * B * (D * D);   // B*NH*4096    = 2 MB
    float* W  = H + (size_t)B * NH * (D * D);        // B*4096       = 256 KB

    for (int layer = 0; layer < NL; ++layer) {
        const float* src = (layer == 0) ? Z : (const float*)out;
        kA <<<dim3(B, CHUNKS), 256, 0, stream>>>(src, Gp);
        kB <<<dim3(B, NH),     256, 0, stream>>>(Gp, allparam, H, layer);
        kB2<<<B,               256, 0, stream>>>(H, W);
        kC <<<dim3(B, S / 64), 256, 0, stream>>>(src, W, out);
    }
}

// Round 2
// 210.452 us; speedup vs baseline: 1.0702x; 1.0702x over previous
//
#include <hip/hip_runtime.h>

constexpr int NH = 8, DP = 63, D = 64, B = 16, S = 2048;
constexpr int TILE = 128, NTILE = 16;      // 128-row tiles, 16 per batch
constexpr float INVS = 1.0f / 2047.0f;

// ---------------------------------------------------------------------------
// Shared gram body: ZN is a [128][64] fp32 tile in LDS, swizzled so that
// column-group g of row n lives at word n*64 + 4*(g ^ ((n>>3)&15)).
// Computes G_partial[q][r] = sum_m ZN[m][q]*ZN[m][r] (per-wave over 32 m's),
// reduces the 4 wave-partials through LDS (overlaying sm4[0..4096) which is
// dead by now), and stores one 64x64 partial to gp.
// ---------------------------------------------------------------------------
__device__ __forceinline__ void gram_reduce_store(const float* ZN, float4* sm4,
                                                  float* __restrict__ gp, int t) {
    const int w = t >> 6, l = t & 63, qy = l >> 3, rx = l & 7;
    float g[8][8];
#pragma unroll
    for (int a = 0; a < 8; ++a)
#pragma unroll
        for (int bb = 0; bb < 8; ++bb) g[a][bb] = 0.f;

#pragma unroll 4
    for (int mi = 0; mi < 32; ++mi) {
        const int m = 32 * w + mi;
        const int f = (m >> 3) & 15;
        const float* rowp = &ZN[m * 64];
        float4 a0 = *(const float4*)&rowp[4 * (qy ^ f)];
        float4 a1 = *(const float4*)&rowp[4 * ((qy + 8) ^ f)];
        float4 b0 = *(const float4*)&rowp[4 * (rx ^ f)];
        float4 b1 = *(const float4*)&rowp[4 * ((rx + 8) ^ f)];
        float A[8]  = {a0.x, a0.y, a0.z, a0.w, a1.x, a1.y, a1.z, a1.w};
        float Bv[8] = {b0.x, b0.y, b0.z, b0.w, b1.x, b1.y, b1.z, b1.w};
#pragma unroll
        for (int a = 0; a < 8; ++a)
#pragma unroll
            for (int bb = 0; bb < 8; ++bb) g[a][bb] += A[a] * Bv[bb];
    }
    __syncthreads();  // all ZN reads complete before overlay writes

    // wave w's partial -> sm4[w*1024 .. w*1024+1024) float4s (16 KB)
    float* part = (float*)(sm4 + w * 1024);
#pragma unroll
    for (int a = 0; a < 8; ++a) {
        const int q = 4 * qy + (a & 3) + 32 * (a >> 2);
        *(float4*)&part[q * 64 + 4 * rx]      = make_float4(g[a][0], g[a][1], g[a][2], g[a][3]);
        *(float4*)&part[q * 64 + 32 + 4 * rx] = make_float4(g[a][4], g[a][5], g[a][6], g[a][7]);
    }
    __syncthreads();

    float4* gp4 = (float4*)gp;
#pragma unroll
    for (int k = 0; k < 4; ++k) {
        const int e4 = t + 256 * k;
        float4 s0 = sm4[e4], s1 = sm4[1024 + e4], s2 = sm4[2048 + e4], s3 = sm4[3072 + e4];
        gp4[e4] = make_float4(s0.x + s1.x + s2.x + s3.x, s0.y + s1.y + s2.y + s3.y,
                              s0.z + s1.z + s2.z + s3.z, s0.w + s1.w + s2.w + s3.w);
    }
}

// ---------------------------------------------------------------------------
// kGram0: Gram partials of the INPUT Z (layer 0 only).  grid (B, NTILE) x 256.
// ---------------------------------------------------------------------------
__global__ __launch_bounds__(256) void kGram0(const float* __restrict__ Z,
                                              float* __restrict__ Gp) {
    __shared__ float4 sm4[5120];                 // 80 KB
    float* ZN = (float*)(sm4 + 3072);            // [128][64] swizzled
    const int b = blockIdx.x, tile = blockIdx.y, t = threadIdx.x;
#pragma unroll
    for (int k = 0; k < 8; ++k) {
        const int row = (t >> 4) + 16 * k, c4 = t & 15;
        const int grow = tile * TILE + row;
        float4 v = *(const float4*)&Z[((size_t)b * S + grow) * D + 4 * c4];
        if (grow == S - 1) v = make_float4(0.f, 0.f, 0.f, 0.f);   // mask last token
        *(float4*)&ZN[row * 64 + 4 * (c4 ^ ((row >> 3) & 15))] = v;
    }
    __syncthreads();
    gram_reduce_store(ZN, sm4, Gp + ((size_t)(b * 16 + tile)) * 4096, t);
}

// ---------------------------------------------------------------------------
// kRed: G[b] = sum of 16 partials; also W[b] = I.   grid (B, 16) x 256.
// ---------------------------------------------------------------------------
__global__ __launch_bounds__(256) void kRed(const float* __restrict__ Gp,
                                            float* __restrict__ G,
                                            float* __restrict__ W) {
    const int b = blockIdx.x, s = blockIdx.y, t = threadIdx.x;
    const int e = s * 256 + t;
    float sum = 0.f;
#pragma unroll 4
    for (int p = 0; p < 16; ++p) sum += Gp[((size_t)(b * 16 + p)) * 4096 + e];
    G[(size_t)b * 4096 + e] = sum;
    W[(size_t)b * 4096 + e] = ((e >> 6) == (e & 63)) ? 1.f : 0.f;
}

// ---------------------------------------------------------------------------
// kW: per (b, head j, col-half s): T = G @ Pfull^T (cols 32s..32s+31),
//     H-slice = Qfull @ T * INVS, atomicAdd into W[b].
// grid (B, NH, 2) x 128.  Uses G's symmetry for b128 A-frag reads.
// ---------------------------------------------------------------------------
__global__ __launch_bounds__(128) void kW(const float* __restrict__ G,
                                          const float* __restrict__ params,  // layer base: [j][2][63][63]
                                          float* __restrict__ W) {
    __shared__ float4 sm4[(4096 + 2048 + 4096 + 2048) / 4];
    float* Gs = (float*)sm4;      // [64][64] linear (symmetric)
    float* Pt = Gs + 4096;        // Pfull^T slice [64][32], swizzled
    float* Qt = Pt + 2048;        // Qfull^T [64][64], swizzled
    float* T  = Qt + 4096;        // [64][32] plain
    const int b = blockIdx.x, j = blockIdx.y, s = blockIdx.z, t = threadIdx.x;
    const int ty = t >> 3, tx = t & 7;
    const float* P = params + (size_t)(j * 2 + 0) * (DP * DP);
    const float* Q = params + (size_t)(j * 2 + 1) * (DP * DP);

#pragma unroll
    for (int k = 0; k < 8; ++k)
        ((float4*)Gs)[t + 128 * k] = ((const float4*)(G + (size_t)b * 4096))[t + 128 * k];
#pragma unroll
    for (int k = 0; k < 16; ++k) {
        const int r = t & 63, ii = (t >> 6) + 2 * k;   // ii in 0..31
        const int i = 32 * s + ii;
        float v = 0.f;
        if (r < DP && i < DP) v = P[(size_t)i * DP + r];
        else if (r == DP && i == DP) v = 1.f;          // Pfull corner
        Pt[r * 32 + 4 * ((ii >> 2) ^ (r & 7)) + (ii & 3)] = v;
    }
#pragma unroll
    for (int k = 0; k < 32; ++k) {
        const int q = t & 63, p = (t >> 6) + 2 * k;    // p in 0..63
        const float v = (p < DP && q < DP) ? Q[(size_t)p * DP + q] : 0.f;  // Qfull corner = 0
        Qt[q * 64 + 4 * ((p >> 2) ^ (q & 15)) + (p & 3)] = v;
    }
    __syncthreads();

    // mm1: T[q][ii] = sum_r G[q][r] * Pfull^T[r][i]   (G[q][r] = G[r][q])
    float acc[4][4] = {};
#pragma unroll 4
    for (int r = 0; r < 64; ++r) {
        float4 av = *(const float4*)&Gs[r * 64 + 4 * ty];
        float4 bv = *(const float4*)&Pt[r * 32 + 4 * (tx ^ (r & 7))];
        float A[4] = {av.x, av.y, av.z, av.w}, Bb[4] = {bv.x, bv.y, bv.z, bv.w};
#pragma unroll
        for (int a = 0; a < 4; ++a)
#pragma unroll
            for (int c = 0; c < 4; ++c) acc[a][c] += A[a] * Bb[c];
    }
#pragma unroll
    for (int a = 0; a < 4; ++a)
        *(float4*)&T[(4 * ty + a) * 32 + 4 * tx] =
            make_float4(acc[a][0], acc[a][1], acc[a][2], acc[a][3]);
    __syncthreads();

    // mm2: H[p][i] = sum_q Qfull[p][q] * T[q][ii]
    float acc2[4][4] = {};
#pragma unroll 4
    for (int q = 0; q < 64; ++q) {
        float4 av = *(const float4*)&Qt[q * 64 + 4 * (ty ^ (q & 15))];
        float4 bv = *(const float4*)&T[q * 32 + 4 * tx];
        float A[4] = {av.x, av.y, av.z, av.w}, Bb[4] = {bv.x, bv.y, bv.z, bv.w};
#pragma unroll
        for (int a = 0; a < 4; ++a)
#pragma unroll
            for (int c = 0; c < 4; ++c) acc2[a][c] += A[a] * Bb[c];
    }
    float* Wb = W + (size_t)b * 4096;
#pragma unroll
    for (int a = 0; a < 4; ++a)
#pragma unroll
        for (int c = 0; c < 4; ++c)
            atomicAdd(&Wb[(4 * ty + a) * 64 + 32 * s + 4 * tx + c], acc2[a][c] * INVS);
}

// ---------------------------------------------------------------------------
// kCA: Znew = Zin @ W[b] (W includes I), write global, and (if do_gram)
//      emit next layer's Gram partial for this 128-row tile.
// grid (B, NTILE) x 256.  In-place safe (block owns its rows).
// ---------------------------------------------------------------------------
__global__ __launch_bounds__(256) void kCA(const float* __restrict__ src,
                                           const float* __restrict__ W,
                                           float* __restrict__ out,
                                           float* __restrict__ Gp, int do_gram) {
    __shared__ float4 sm4[5120];                 // 80 KB
    float* ZT = (float*)sm4;                     // Zin^T [64][128] swizzled
    float* Ws = (float*)(sm4 + 2048);            // W[b] [64][64] linear
    float* ZN = (float*)(sm4 + 3072);            // Znew [128][64] swizzled
    const int b = blockIdx.x, tile = blockIdx.y, t = threadIdx.x;
    const int ny = t & 15, ix = t >> 4;
    const size_t zbase = ((size_t)b * S + tile * TILE) * D;

#pragma unroll
    for (int k = 0; k < 4; ++k)
        sm4[2048 + t + 256 * k] = ((const float4*)(W + (size_t)b * 4096))[t + 256 * k];
#pragma unroll
    for (int k = 0; k < 8; ++k) {
        const int row = (t >> 4) + 16 * k, c4 = t & 15;
        float4 v = *(const float4*)&src[zbase + (size_t)row * D + 4 * c4];
        float vv[4] = {v.x, v.y, v.z, v.w};
#pragma unroll
        for (int c = 0; c < 4; ++c) {
            const int p = 4 * c4 + c;
            ZT[p * 128 + 4 * ((row >> 2) ^ c4) + (row & 3)] = vv[c];
        }
    }
    __syncthreads();

    // apply: rows {4ny..4ny+3} and {64+4ny..64+4ny+3}, cols {4ix..4ix+3}
    float acc[8][4] = {};
#pragma unroll 4
    for (int p = 0; p < 64; ++p) {
        const int f = p >> 2;
        const float* zp = &ZT[p * 128];
        float4 a0 = *(const float4*)&zp[4 * (ny ^ f)];
        float4 a1 = *(const float4*)&zp[4 * ((ny + 16) ^ f)];
        float4 wv = *(const float4*)&Ws[p * 64 + 4 * ix];
        float A[8] = {a0.x, a0.y, a0.z, a0.w, a1.x, a1.y, a1.z, a1.w};
        float Wv[4] = {wv.x, wv.y, wv.z, wv.w};
#pragma unroll
        for (int a = 0; a < 8; ++a)
#pragma unroll
            for (int c = 0; c < 4; ++c) acc[a][c] += A[a] * Wv[c];
    }
#pragma unroll
    for (int a = 0; a < 8; ++a) {
        const int n = 4 * ny + (a & 3) + 64 * (a >> 2);
        *(float4*)&out[zbase + (size_t)n * D + 4 * ix] =
            make_float4(acc[a][0], acc[a][1], acc[a][2], acc[a][3]);
    }
    if (!do_gram) return;

#pragma unroll
    for (int a = 0; a < 8; ++a) {
        const int n = 4 * ny + (a & 3) + 64 * (a >> 2);
        float4 vv = make_float4(acc[a][0], acc[a][1], acc[a][2], acc[a][3]);
        if (tile == NTILE - 1 && n == TILE - 1) vv = make_float4(0.f, 0.f, 0.f, 0.f);
        *(float4*)&ZN[n * 64 + 4 * (ix ^ ((n >> 3) & 15))] = vv;
    }
    __syncthreads();
    gram_reduce_store(ZN, sm4, Gp + ((size_t)(b * 16 + tile)) * 4096, t);
}

// ---------------------------------------------------------------------------
extern "C" void kernel_launch(void* const* d_in, const int* in_sizes, int n_in,
                              void* d_out, int out_size, void* d_ws, size_t ws_size,
                              hipStream_t stream) {
    const float* Z        = (const float*)d_in[0];
    const float* allparam = (const float*)d_in[1];
    float* out = (float*)d_out;

    float* Gp = (float*)d_ws;                   // B*16*4096 = 4 MB
    float* G  = Gp + (size_t)B * 16 * 4096;     // B*4096
    float* W  = G + (size_t)B * 4096;           // B*4096

    kGram0<<<dim3(B, NTILE), 256, 0, stream>>>(Z, Gp);
    for (int layer = 0; layer < 4; ++layer) {
        const float* src = (layer == 0) ? Z : (const float*)out;
        const float* params = allparam + (size_t)layer * NH * 2 * DP * DP;
        kRed<<<dim3(B, 16), 256, 0, stream>>>(Gp, G, W);
        kW<<<dim3(B, NH, 2), 128, 0, stream>>>(G, params, W);
        kCA<<<dim3(B, NTILE), 256, 0, stream>>>(src, W, out, Gp, layer < 3 ? 1 : 0);
    }
}